// Round 6
// baseline (6252.625 us; speedup 1.0000x reference)
//
#include <hip/hip_runtime.h>
#include <stdint.h>

typedef __attribute__((ext_vector_type(8))) short short8;
typedef __attribute__((ext_vector_type(4))) float f32x4;
typedef unsigned long long u64;

constexpr int cB = 32, cT = 512, cD = 512, cH = 512;
constexpr int cKI = 6 * cH;   // 3072
constexpr int NWG = 32;
constexpr int THR = 320;
constexpr int LDW = 40;       // gemm LDS row pitch (shorts)
constexpr int RNG = 3;        // pi prefetch ring depth

__device__ __forceinline__ float bf2f(unsigned short u) {
  union { unsigned int i; float f; } x; x.i = ((unsigned int)u) << 16; return x.f;
}
__device__ __forceinline__ unsigned short f2bf(float f) {
  union { float f; unsigned int i; } x; x.f = f;
  return (unsigned short)((x.i + 0x7fffu + ((x.i >> 16) & 1u)) >> 16);
}
__device__ __forceinline__ float sigm(float v) { return 1.0f / (1.0f + __expf(-v)); }
__device__ __forceinline__ float tanh_f(float v) { return 2.0f / (1.0f + __expf(-2.0f * v)) - 1.0f; }

// ---------------- Phase 1: pi[t][k][b] = x[b][t][:] . Wi[k][:] + bi[k] ----------------
__global__ __launch_bounds__(256) void gemm_pi(
    const float* __restrict__ x,    // [B][T][D] fp32
    const float* __restrict__ Wi,   // [6H][D] fp32
    const float* __restrict__ bi,   // [6H] fp32
    unsigned short* __restrict__ pi)// [T][6H][B] bf16
{
  __shared__ __align__(16) unsigned short Ai[128 * LDW];
  __shared__ __align__(16) unsigned short Bi[128 * LDW];

  const int tid = threadIdx.x;
  const int lane = tid & 63;
  const int w = tid >> 6;
  const int wm = w & 1, wn = w >> 1;
  const int k0 = blockIdx.x * 128;
  const int n0 = blockIdx.y * 128;   // n = t*32 + b

  f32x4 acc[4][4];
  #pragma unroll
  for (int i = 0; i < 4; i++)
    #pragma unroll
    for (int j = 0; j < 4; j++) acc[i][j] = (f32x4){0.f, 0.f, 0.f, 0.f};

  for (int kk = 0; kk < cD; kk += 32) {
    __syncthreads();
    #pragma unroll
    for (int it = 0; it < 4; it++) {
      int idx = tid + it * 256;
      int r = idx >> 3, ch = idx & 7;
      int na = n0 + r;
      int bb = na & 31, tt = na >> 5;
      float4 va = *(const float4*)(x + ((size_t)bb * cT + tt) * cD + kk + ch * 4);
      ushort4 pa; pa.x = f2bf(va.x); pa.y = f2bf(va.y); pa.z = f2bf(va.z); pa.w = f2bf(va.w);
      *(ushort4*)(Ai + r * LDW + ch * 4) = pa;
      float4 vb = *(const float4*)(Wi + (size_t)(k0 + r) * cD + kk + ch * 4);
      ushort4 pb; pb.x = f2bf(vb.x); pb.y = f2bf(vb.y); pb.z = f2bf(vb.z); pb.w = f2bf(vb.w);
      *(ushort4*)(Bi + r * LDW + ch * 4) = pb;
    }
    __syncthreads();

    short8 af[4], bfr[4];
    const int q = lane >> 4;
    #pragma unroll
    for (int mi = 0; mi < 4; mi++) {
      int m = wm * 64 + mi * 16 + (lane & 15);
      af[mi] = *(const short8*)(Ai + m * LDW + q * 8);
    }
    #pragma unroll
    for (int ni = 0; ni < 4; ni++) {
      int n = wn * 64 + ni * 16 + (lane & 15);
      bfr[ni] = *(const short8*)(Bi + n * LDW + q * 8);
    }
    #pragma unroll
    for (int mi = 0; mi < 4; mi++)
      #pragma unroll
      for (int ni = 0; ni < 4; ni++)
        acc[mi][ni] = __builtin_amdgcn_mfma_f32_16x16x32_bf16(af[mi], bfr[ni], acc[mi][ni], 0, 0, 0);
  }

  #pragma unroll
  for (int ni = 0; ni < 4; ni++) {
    int kl = wn * 64 + ni * 16 + (lane & 15);
    float bv = bi[k0 + kl];
    #pragma unroll
    for (int mi = 0; mi < 4; mi++) {
      int nl = wm * 64 + mi * 16 + (lane >> 4) * 4;
      int nb = n0 + nl;
      int b0 = nb & 31, tt = nb >> 5;
      f32x4 a = acc[mi][ni];
      unsigned short v0 = f2bf(a.x + bv), v1 = f2bf(a.y + bv);
      unsigned short v2 = f2bf(a.z + bv), v3 = f2bf(a.w + bv);
      uint2 pv; pv.x = (unsigned)v0 | ((unsigned)v1 << 16);
      pv.y = (unsigned)v2 | ((unsigned)v3 << 16);
      *(uint2*)(pi + ((size_t)tt * cKI + k0 + kl) * cB + b0) = pv;
    }
  }
}

// ---------------- Phase 2: persistent recurrent scan ----------------
// 32 WGs; WG owns 16 ps/h columns. Ws frags in registers; h exchanged via
// agent-relaxed atomics, loaded straight into MFMA A-frags; flag-array barrier.
__global__ __launch_bounds__(THR, 1) void lstm_rec(
    const unsigned short* __restrict__ pi,   // [T][6H][B] bf16
    const float* __restrict__ Ws,            // [5H][H] fp32
    const float* __restrict__ bs,            // [5H] fp32
    const int* __restrict__ lengths,         // [B]
    unsigned short* __restrict__ hbuf,       // [2][B][H] bf16 (coherent-path only)
    int* __restrict__ flags,                 // [NWG]
    float* __restrict__ out)                 // ys[B][T][H], hT[B][H], cT[B][H] fp32
{
  __shared__ __align__(16) unsigned short piL[RNG * 6 * 16 * 32]; // 18.4 KB [slot][g][c][b]
  __shared__ __align__(16) float ps_lds[5 * 16 * 36];             // [gate][c][b pad]
  __shared__ __align__(16) float c_lds[16 * 32];                  // [c][b]
  __shared__ __align__(16) unsigned short hstg[16 * 32];          // prev h, own slice [c][b]
  __shared__ float bs_lds[80];
  __shared__ int len_lds[32];

  const int tid = threadIdx.x;
  const int lane = tid & 63;
  const int w = tid >> 6;          // wave = gate (0..4)
  const int wg = blockIdx.x;
  const int ci0 = wg * 16;
  const int mc = lane & 15;
  const int kq = lane >> 4;

  // B-fragments (Ws) resident in registers: lane covers ws-global row w*H + ci0 + mc
  short8 bfrag[16];
  {
    const float* wsrow = Ws + (size_t)(w * cH + ci0 + mc) * cH;
    #pragma unroll
    for (int kt = 0; kt < 16; kt++) {
      float4 f0 = *(const float4*)(wsrow + kt * 32 + kq * 8);
      float4 f1 = *(const float4*)(wsrow + kt * 32 + kq * 8 + 4);
      short8 pk;
      pk[0] = (short)f2bf(f0.x); pk[1] = (short)f2bf(f0.y);
      pk[2] = (short)f2bf(f0.z); pk[3] = (short)f2bf(f0.w);
      pk[4] = (short)f2bf(f1.x); pk[5] = (short)f2bf(f1.y);
      pk[6] = (short)f2bf(f1.z); pk[7] = (short)f2bf(f1.w);
      bfrag[kt] = pk;
    }
  }
  if (tid < 80) bs_lds[tid] = bs[(tid >> 4) * cH + ci0 + (tid & 15)];
  if (tid < cB) len_lds[tid] = lengths[tid];
  for (int q = tid; q < 16 * 32; q += THR) { c_lds[q] = 0.0f; hstg[q] = 0; }

  // pi ring prologue: t=0 -> slot0, t=1 -> slot1
  for (int s = 0; s < 2; s++) {
    const unsigned short* pit = pi + (size_t)s * cKI * cB;
    for (int j = tid; j < 384; j += THR) {
      int g = j >> 6, rem = j & 63, c = rem >> 2, q = rem & 3;
      uint4 v = *(const uint4*)(pit + ((size_t)g * cH + ci0 + c) * cB + q * 8);
      *(uint4*)(piL + s * 3072 + (g * 16 + c) * 32 + q * 8) = v;
    }
  }
  // zero own slice of hbuf[0] (h0 = 0), publish readiness via flag=1
  if (tid < 128) {
    int b = tid >> 2, q = tid & 3;
    u64* hd0 = (u64*)hbuf;
    __hip_atomic_store(hd0 + b * 128 + (ci0 >> 2) + q, 0ull, __ATOMIC_RELAXED, __HIP_MEMORY_SCOPE_AGENT);
  }
  __syncthreads();   // drains zero-stores (vmcnt) + LDS init
  if (tid == 0)
    __hip_atomic_store(&flags[wg], 1, __ATOMIC_RELAXED, __HIP_MEMORY_SCOPE_AGENT);
  if (tid < 32) {
    while (true) {
      int f = __hip_atomic_load(&flags[tid], __ATOMIC_RELAXED, __HIP_MEMORY_SCOPE_AGENT);
      if (__all(f >= 1)) break;
    }
  }
  __syncthreads();

  for (int t = 0; t < cT; t++) {
    // [P] pi global loads for step t+2 (overlap whole step)
    uint4 pv0, pv1;
    const bool pf = (t + 2) < cT;
    const int slot_w = (t + 2) % RNG;
    if (pf) {
      const unsigned short* pit = pi + (size_t)(t + 2) * cKI * cB;
      { int g = tid >> 6, rem = tid & 63, c = rem >> 2, q = rem & 3;
        pv0 = *(const uint4*)(pit + ((size_t)g * cH + ci0 + c) * cB + q * 8); }
      int j1 = tid + THR;
      if (j1 < 384) { int g = j1 >> 6, rem = j1 & 63, c = rem >> 2, q = rem & 3;
        pv1 = *(const uint4*)(pit + ((size_t)g * cH + ci0 + c) * cB + q * 8); }
    }
    // [A] h -> MFMA A-frags directly (agent-relaxed u64 loads, coherence-safe)
    const unsigned short* hsrc = hbuf + (size_t)(t & 1) * cB * cH;
    u64 av[64];
    #pragma unroll
    for (int kt = 0; kt < 16; kt++) {
      const u64* p0 = (const u64*)(hsrc + mc * cH + kt * 32 + kq * 8);
      const u64* p1 = (const u64*)(hsrc + (16 + mc) * cH + kt * 32 + kq * 8);
      av[kt*4+0] = __hip_atomic_load(p0,     __ATOMIC_RELAXED, __HIP_MEMORY_SCOPE_AGENT);
      av[kt*4+1] = __hip_atomic_load(p0 + 1, __ATOMIC_RELAXED, __HIP_MEMORY_SCOPE_AGENT);
      av[kt*4+2] = __hip_atomic_load(p1,     __ATOMIC_RELAXED, __HIP_MEMORY_SCOPE_AGENT);
      av[kt*4+3] = __hip_atomic_load(p1 + 1, __ATOMIC_RELAXED, __HIP_MEMORY_SCOPE_AGENT);
    }
    // [D] MFMA: 32x16 tile, K=512
    f32x4 acc0 = (f32x4){0.f,0.f,0.f,0.f}, acc1 = (f32x4){0.f,0.f,0.f,0.f};
    #pragma unroll
    for (int kt = 0; kt < 16; kt++) {
      union { u64 q[2]; short8 s; } ua0, ua1;
      ua0.q[0] = av[kt*4+0]; ua0.q[1] = av[kt*4+1];
      ua1.q[0] = av[kt*4+2]; ua1.q[1] = av[kt*4+3];
      acc0 = __builtin_amdgcn_mfma_f32_16x16x32_bf16(ua0.s, bfrag[kt], acc0, 0, 0, 0);
      acc1 = __builtin_amdgcn_mfma_f32_16x16x32_bf16(ua1.s, bfrag[kt], acc1, 0, 0, 0);
    }
    {
      int r0 = kq * 4;   // C layout: col=lane&15 (=c), rows=(lane>>4)*4+reg (=b)
      *(f32x4*)(ps_lds + (w * 16 + mc) * 36 + r0) = acc0;
      *(f32x4*)(ps_lds + (w * 16 + mc) * 36 + r0 + 16) = acc1;
    }
    // [E] pi ring write for t+2
    if (pf) {
      { int g = tid >> 6, rem = tid & 63, c = rem >> 2, q = rem & 3;
        *(uint4*)(piL + slot_w * 3072 + (g * 16 + c) * 32 + q * 8) = pv0; }
      int j1 = tid + THR;
      if (j1 < 384) { int g = j1 >> 6, rem = j1 & 63, c = rem >> 2, q = rem & 3;
        *(uint4*)(piL + slot_w * 3072 + (g * 16 + c) * 32 + q * 8) = pv1; }
    }
    __syncthreads();   // S1: ps + ring visible

    // [F] gates (fp32) + fused publish
    const unsigned short* pl = piL + (t % RNG) * 3072;
    unsigned short* hdst = hbuf + (size_t)((t + 1) & 1) * cB * cH;
    #pragma unroll
    for (int u = 0; u < 2; u++) {
      int idx = tid + u * THR;
      if (idx < 512) {
        int b = idx & 31, c = idx >> 5;
        int col = ci0 + c;
        float a_i = bf2f(pl[(0*16 + c)*32 + b]) + ps_lds[(0*16 + c)*36 + b] + bs_lds[0*16 + c];
        float a_f = bf2f(pl[(1*16 + c)*32 + b]) + ps_lds[(1*16 + c)*36 + b] + bs_lds[1*16 + c];
        float a_g = bf2f(pl[(2*16 + c)*32 + b]) + ps_lds[(2*16 + c)*36 + b] + bs_lds[2*16 + c];
        float a_o = bf2f(pl[(3*16 + c)*32 + b]) + ps_lds[(3*16 + c)*36 + b] + bs_lds[3*16 + c];
        float a_r = bf2f(pl[(4*16 + c)*32 + b]) + ps_lds[(4*16 + c)*36 + b] + bs_lds[4*16 + c];
        float p5  = bf2f(pl[(5*16 + c)*32 + b]);
        float gi = sigm(a_i), gf = sigm(a_f), gg = tanh_f(a_g), go = sigm(a_o), gr = sigm(a_r);
        float cold = c_lds[c * 32 + b];
        float cn = gi * gg + gf * cold;
        float ov = go * tanh_f(cn);
        ov = gr * ov + (1.0f - gr) * p5;
        bool m = (t < len_lds[b]);
        float hold = bf2f(hstg[c * 32 + b]);
        float hn = m ? ov : hold;
        c_lds[c * 32 + b] = m ? cn : cold;
        unsigned short hb = f2bf(hn);
        hstg[c * 32 + b] = hb;
        out[((size_t)b * cT + t) * cH + col] = m ? ov : 0.0f;
        if (t == cT - 1)
          out[(size_t)cB * cT * cH + (size_t)b * cH + col] = hn;   // hT
        else
          __hip_atomic_store(&hdst[b * cH + col], hb, __ATOMIC_RELAXED, __HIP_MEMORY_SCOPE_AGENT);
      }
    }
    // barrier (skip after last step)
    if (t + 1 < cT) {
      __syncthreads();   // S2: drains publish + ys stores (vmcnt 0 before s_barrier)
      if (tid == 0)
        __hip_atomic_store(&flags[wg], t + 2, __ATOMIC_RELAXED, __HIP_MEMORY_SCOPE_AGENT);
      if (tid < 32) {
        while (true) {
          int f = __hip_atomic_load(&flags[tid], __ATOMIC_RELAXED, __HIP_MEMORY_SCOPE_AGENT);
          if (__all(f >= t + 2)) break;
        }
      }
      __syncthreads();   // S3: release
    }
  }

  // cT from local c state (same thread mapping as gates -> no sync needed)
  #pragma unroll
  for (int u = 0; u < 2; u++) {
    int idx = tid + u * THR;
    if (idx < 512) {
      int b = idx & 31, c = idx >> 5;
      out[(size_t)cB * cT * cH + (size_t)cB * cH + (size_t)b * cH + ci0 + c] = c_lds[c * 32 + b];
    }
  }
}

extern "C" void kernel_launch(void* const* d_in, const int* in_sizes, int n_in,
                              void* d_out, int out_size, void* d_ws, size_t ws_size,
                              hipStream_t stream) {
  const float* x       = (const float*)d_in[0];
  const int* lengths   = (const int*)d_in[1];
  const float* Wi      = (const float*)d_in[2];
  const float* bi      = (const float*)d_in[3];
  const float* Ws      = (const float*)d_in[4];
  const float* bs      = (const float*)d_in[5];
  float* out = (float*)d_out;

  char* ws = (char*)d_ws;
  int* flags = (int*)ws;
  unsigned short* hbuf = (unsigned short*)(ws + 512);       // 2*32*512*2 = 64KB
  unsigned short* pi   = (unsigned short*)(ws + (1 << 20)); // [512][3072][32] bf16

  hipMemsetAsync(flags, 0, 256, stream);
  dim3 grid1(cKI / 128, (cB * cT) / 128);
  gemm_pi<<<grid1, 256, 0, stream>>>(x, Wi, bi, pi);
  lstm_rec<<<NWG, THR, 0, stream>>>(pi, Ws, bs, lengths, hbuf, flags, out);
}

// Round 7
// 2002.333 us; speedup vs baseline: 3.1227x; 3.1227x over previous
//
#include <hip/hip_runtime.h>
#include <stdint.h>

typedef __attribute__((ext_vector_type(8))) short short8;
typedef __attribute__((ext_vector_type(4))) float f32x4;
typedef unsigned long long u64;

constexpr int cB = 32, cT = 512, cD = 512, cH = 512;
constexpr int cKI = 6 * cH;   // 3072
constexpr int NWG = 32;
constexpr int THR = 320;
constexpr int LDW = 40;       // gemm LDS row pitch (shorts)
constexpr int HP  = 520;      // rec LDS row pitch (shorts)
constexpr int RNG = 3;        // pi prefetch ring depth
constexpr int FPAD = 16;      // flag padding (ints) = 64B

__device__ __forceinline__ float bf2f(unsigned short u) {
  union { unsigned int i; float f; } x; x.i = ((unsigned int)u) << 16; return x.f;
}
__device__ __forceinline__ unsigned short f2bf(float f) {
  union { float f; unsigned int i; } x; x.f = f;
  return (unsigned short)((x.i + 0x7fffu + ((x.i >> 16) & 1u)) >> 16);
}
__device__ __forceinline__ float sigm(float v) { return 1.0f / (1.0f + __expf(-v)); }
__device__ __forceinline__ float tanh_f(float v) { return 2.0f / (1.0f + __expf(-2.0f * v)) - 1.0f; }

// ---------------- Phase 1: pi[t][k][b] = x[b][t][:] . Wi[k][:] + bi[k] ----------------
__global__ __launch_bounds__(256) void gemm_pi(
    const float* __restrict__ x,    // [B][T][D] fp32
    const float* __restrict__ Wi,   // [6H][D] fp32
    const float* __restrict__ bi,   // [6H] fp32
    unsigned short* __restrict__ pi)// [T][6H][B] bf16
{
  __shared__ __align__(16) unsigned short Ai[128 * LDW];
  __shared__ __align__(16) unsigned short Bi[128 * LDW];

  const int tid = threadIdx.x;
  const int lane = tid & 63;
  const int w = tid >> 6;
  const int wm = w & 1, wn = w >> 1;
  const int k0 = blockIdx.x * 128;
  const int n0 = blockIdx.y * 128;   // n = t*32 + b

  f32x4 acc[4][4];
  #pragma unroll
  for (int i = 0; i < 4; i++)
    #pragma unroll
    for (int j = 0; j < 4; j++) acc[i][j] = (f32x4){0.f, 0.f, 0.f, 0.f};

  for (int kk = 0; kk < cD; kk += 32) {
    __syncthreads();
    #pragma unroll
    for (int it = 0; it < 4; it++) {
      int idx = tid + it * 256;
      int r = idx >> 3, ch = idx & 7;
      int na = n0 + r;
      int bb = na & 31, tt = na >> 5;
      float4 va = *(const float4*)(x + ((size_t)bb * cT + tt) * cD + kk + ch * 4);
      ushort4 pa; pa.x = f2bf(va.x); pa.y = f2bf(va.y); pa.z = f2bf(va.z); pa.w = f2bf(va.w);
      *(ushort4*)(Ai + r * LDW + ch * 4) = pa;
      float4 vb = *(const float4*)(Wi + (size_t)(k0 + r) * cD + kk + ch * 4);
      ushort4 pb; pb.x = f2bf(vb.x); pb.y = f2bf(vb.y); pb.z = f2bf(vb.z); pb.w = f2bf(vb.w);
      *(ushort4*)(Bi + r * LDW + ch * 4) = pb;
    }
    __syncthreads();

    short8 af[4], bfr[4];
    const int q = lane >> 4;
    #pragma unroll
    for (int mi = 0; mi < 4; mi++) {
      int m = wm * 64 + mi * 16 + (lane & 15);
      af[mi] = *(const short8*)(Ai + m * LDW + q * 8);
    }
    #pragma unroll
    for (int ni = 0; ni < 4; ni++) {
      int n = wn * 64 + ni * 16 + (lane & 15);
      bfr[ni] = *(const short8*)(Bi + n * LDW + q * 8);
    }
    #pragma unroll
    for (int mi = 0; mi < 4; mi++)
      #pragma unroll
      for (int ni = 0; ni < 4; ni++)
        acc[mi][ni] = __builtin_amdgcn_mfma_f32_16x16x32_bf16(af[mi], bfr[ni], acc[mi][ni], 0, 0, 0);
  }

  #pragma unroll
  for (int ni = 0; ni < 4; ni++) {
    int kl = wn * 64 + ni * 16 + (lane & 15);
    float bv = bi[k0 + kl];
    #pragma unroll
    for (int mi = 0; mi < 4; mi++) {
      int nl = wm * 64 + mi * 16 + (lane >> 4) * 4;
      int nb = n0 + nl;
      int b0 = nb & 31, tt = nb >> 5;
      f32x4 a = acc[mi][ni];
      unsigned short v0 = f2bf(a.x + bv), v1 = f2bf(a.y + bv);
      unsigned short v2 = f2bf(a.z + bv), v3 = f2bf(a.w + bv);
      uint2 pv; pv.x = (unsigned)v0 | ((unsigned)v1 << 16);
      pv.y = (unsigned)v2 | ((unsigned)v3 << 16);
      *(uint2*)(pi + ((size_t)tt * cKI + k0 + kl) * cB + b0) = pv;
    }
  }
}

// ---------------- Phase 2: persistent recurrent scan ----------------
// R5 skeleton (coalesced batch h exchange via LDS) + flag barrier + register Ws.
__global__ __launch_bounds__(THR, 1) void lstm_rec(
    const unsigned short* __restrict__ pi,   // [T][6H][B] bf16
    const float* __restrict__ Ws,            // [5H][H] fp32
    const float* __restrict__ bs,            // [5H] fp32
    const int* __restrict__ lengths,         // [B]
    unsigned short* __restrict__ hbuf,       // [2][B][H] bf16 (coherent-path only)
    int* __restrict__ flags,                 // [NWG*FPAD]
    float* __restrict__ out)                 // ys[B][T][H], hT[B][H], cT[B][H] fp32
{
  __shared__ __align__(16) unsigned short h_lds[32 * HP];         // 33.3 KB
  __shared__ __align__(16) unsigned short piL[RNG * 6 * 16 * 32]; // 18.4 KB [slot][g][c][b]
  __shared__ __align__(16) float ps_lds[5 * 16 * 36];             // [gate][c][b pad]
  __shared__ __align__(16) float c_lds[16 * 32];                  // [c][b]
  __shared__ __align__(16) unsigned short hstg[16 * 32];          // new h, own slice [c][b]
  __shared__ float bs_lds[80];
  __shared__ int len_lds[32];

  const int tid = threadIdx.x;
  const int lane = tid & 63;
  const int w = tid >> 6;          // wave = gate (0..4)
  const int wg = blockIdx.x;
  const int ci0 = wg * 16;
  const int mc = lane & 15;
  const int kq = lane >> 4;

  // Ws B-fragments in registers (verified correct in R6):
  // lane covers Ws row w*H + ci0 + mc, k-chunk kt*32 + kq*8
  short8 bfrag[16];
  {
    const float* wsrow = Ws + (size_t)(w * cH + ci0 + mc) * cH;
    #pragma unroll
    for (int kt = 0; kt < 16; kt++) {
      float4 f0 = *(const float4*)(wsrow + kt * 32 + kq * 8);
      float4 f1 = *(const float4*)(wsrow + kt * 32 + kq * 8 + 4);
      short8 pk;
      pk[0] = (short)f2bf(f0.x); pk[1] = (short)f2bf(f0.y);
      pk[2] = (short)f2bf(f0.z); pk[3] = (short)f2bf(f0.w);
      pk[4] = (short)f2bf(f1.x); pk[5] = (short)f2bf(f1.y);
      pk[6] = (short)f2bf(f1.z); pk[7] = (short)f2bf(f1.w);
      bfrag[kt] = pk;
    }
  }
  if (tid < 80) bs_lds[tid] = bs[(tid >> 4) * cH + ci0 + (tid & 15)];
  if (tid < cB) len_lds[tid] = lengths[tid];
  for (int q = tid; q < 16 * 32; q += THR) c_lds[q] = 0.0f;
  for (int q = tid; q < 32 * HP / 4; q += THR) ((u64*)h_lds)[q] = 0ull;   // h0 = 0

  // pi ring prologue: t=0 -> slot0, t=1 -> slot1
  for (int s = 0; s < 2; s++) {
    const unsigned short* pit = pi + (size_t)s * cKI * cB;
    for (int j = tid; j < 384; j += THR) {
      int g = j >> 6, rem = j & 63, c = rem >> 2, q = rem & 3;
      uint4 v = *(const uint4*)(pit + ((size_t)g * cH + ci0 + c) * cB + q * 8);
      *(uint4*)(piL + s * 3072 + (g * 16 + c) * 32 + q * 8) = v;
    }
  }
  // zero own slice of hbuf[0]; publish readiness flag=1
  if (tid < 128) {
    int b = tid >> 2, q = tid & 3;
    u64* hd0 = (u64*)hbuf;
    __hip_atomic_store(hd0 + b * 128 + (ci0 >> 2) + q, 0ull, __ATOMIC_RELAXED, __HIP_MEMORY_SCOPE_AGENT);
  }
  __syncthreads();   // drains zero-stores (vmcnt) + LDS init
  if (tid == 0)
    __hip_atomic_store(&flags[wg * FPAD], 1, __ATOMIC_RELAXED, __HIP_MEMORY_SCOPE_AGENT);
  if (tid < 32) {
    while (true) {
      int f = __hip_atomic_load(&flags[tid * FPAD], __ATOMIC_RELAXED, __HIP_MEMORY_SCOPE_AGENT);
      if (__all(f >= 1)) break;
    }
  }
  __syncthreads();

  for (int t = 0; t < cT; t++) {
    // [A] h batch loads via coherent path, fully coalesced (skip t=0: LDS zeroed)
    u64 hv[13];
    if (t > 0) {
      u64* hs = (u64*)(hbuf + (size_t)(t & 1) * cB * cH);
      #pragma unroll
      for (int k = 0; k < 13; k++) {
        int idx = tid + k * THR;
        if (idx < 4096)
          hv[k] = __hip_atomic_load(hs + idx, __ATOMIC_RELAXED, __HIP_MEMORY_SCOPE_AGENT);
      }
    }
    // [P] pi global loads for step t+2 (in flight across the whole step)
    uint4 pv0, pv1;
    const bool pf = (t + 2) < cT;
    const int slot_w = (t + 2) % RNG;
    if (pf) {
      const unsigned short* pit = pi + (size_t)(t + 2) * cKI * cB;
      { int g = tid >> 6, rem = tid & 63, c = rem >> 2, q = rem & 3;
        pv0 = *(const uint4*)(pit + ((size_t)g * cH + ci0 + c) * cB + q * 8); }
      int j1 = tid + THR;
      if (j1 < 384) { int g = j1 >> 6, rem = j1 & 63, c = rem >> 2, q = rem & 3;
        pv1 = *(const uint4*)(pit + ((size_t)g * cH + ci0 + c) * cB + q * 8); }
    }
    // [C] write staged h into LDS
    if (t > 0) {
      #pragma unroll
      for (int k = 0; k < 13; k++) {
        int idx = tid + k * THR;
        if (idx < 4096) {
          int b = idx >> 7, ch = idx & 127;
          *(u64*)(h_lds + b * HP + ch * 4) = hv[k];
        }
      }
    }
    __syncthreads();

    // [D] MFMA: wave w computes ps[:, gate w] : 32x16, K=512 (Ws from registers)
    f32x4 acc0 = (f32x4){0.f,0.f,0.f,0.f}, acc1 = (f32x4){0.f,0.f,0.f,0.f};
    #pragma unroll
    for (int kt = 0; kt < 16; kt++) {
      int kc = kt * 4 + kq;
      short8 a0 = *(const short8*)(h_lds + mc * HP + kc * 8);
      short8 a1 = *(const short8*)(h_lds + (16 + mc) * HP + kc * 8);
      acc0 = __builtin_amdgcn_mfma_f32_16x16x32_bf16(a0, bfrag[kt], acc0, 0, 0, 0);
      acc1 = __builtin_amdgcn_mfma_f32_16x16x32_bf16(a1, bfrag[kt], acc1, 0, 0, 0);
    }
    {
      int r0 = kq * 4;   // C layout: col=lane&15 (=c), rows=(lane>>4)*4+reg (=b)
      *(f32x4*)(ps_lds + (w * 16 + mc) * 36 + r0) = acc0;
      *(f32x4*)(ps_lds + (w * 16 + mc) * 36 + r0 + 16) = acc1;
    }
    // [E] pi ring write for t+2
    if (pf) {
      { int g = tid >> 6, rem = tid & 63, c = rem >> 2, q = rem & 3;
        *(uint4*)(piL + slot_w * 3072 + (g * 16 + c) * 32 + q * 8) = pv0; }
      int j1 = tid + THR;
      if (j1 < 384) { int g = j1 >> 6, rem = j1 & 63, c = rem >> 2, q = rem & 3;
        *(uint4*)(piL + slot_w * 3072 + (g * 16 + c) * 32 + q * 8) = pv1; }
    }
    __syncthreads();   // S1: ps + ring visible

    // [F] gates (fp32)
    const unsigned short* pl = piL + (t % RNG) * 3072;
    #pragma unroll
    for (int u = 0; u < 2; u++) {
      int idx = tid + u * THR;
      if (idx < 512) {
        int b = idx & 31, c = idx >> 5;
        int col = ci0 + c;
        float a_i = bf2f(pl[(0*16 + c)*32 + b]) + ps_lds[(0*16 + c)*36 + b] + bs_lds[0*16 + c];
        float a_f = bf2f(pl[(1*16 + c)*32 + b]) + ps_lds[(1*16 + c)*36 + b] + bs_lds[1*16 + c];
        float a_g = bf2f(pl[(2*16 + c)*32 + b]) + ps_lds[(2*16 + c)*36 + b] + bs_lds[2*16 + c];
        float a_o = bf2f(pl[(3*16 + c)*32 + b]) + ps_lds[(3*16 + c)*36 + b] + bs_lds[3*16 + c];
        float a_r = bf2f(pl[(4*16 + c)*32 + b]) + ps_lds[(4*16 + c)*36 + b] + bs_lds[4*16 + c];
        float p5  = bf2f(pl[(5*16 + c)*32 + b]);
        float gi = sigm(a_i), gf = sigm(a_f), gg = tanh_f(a_g), go = sigm(a_o), gr = sigm(a_r);
        float cold = c_lds[c * 32 + b];
        float cn = gi * gg + gf * cold;
        float ov = go * tanh_f(cn);
        ov = gr * ov + (1.0f - gr) * p5;
        bool m = (t < len_lds[b]);
        float hold = bf2f(h_lds[b * HP + col]);
        float hn = m ? ov : hold;
        c_lds[c * 32 + b] = m ? cn : cold;
        hstg[c * 32 + b] = f2bf(hn);
        out[((size_t)b * cT + t) * cH + col] = m ? ov : 0.0f;
        if (t == cT - 1)
          out[(size_t)cB * cT * cH + (size_t)b * cH + col] = hn;   // hT
      }
    }
    if (t + 1 < cT) {
      __syncthreads();   // S2: hstg complete
      // [G] pack & publish h, coalesced 8B chunks (4 lanes -> 32B/row)
      if (tid < 128) {
        int b = tid >> 2, q = tid & 3;
        u64 pk = (u64)hstg[(q*4 + 0)*32 + b] | ((u64)hstg[(q*4 + 1)*32 + b] << 16)
               | ((u64)hstg[(q*4 + 2)*32 + b] << 32) | ((u64)hstg[(q*4 + 3)*32 + b] << 48);
        u64* hd = (u64*)(hbuf + (size_t)((t + 1) & 1) * cB * cH);
        __hip_atomic_store(hd + b * 128 + (ci0 >> 2) + q, pk, __ATOMIC_RELAXED, __HIP_MEMORY_SCOPE_AGENT);
      }
      // [H] flag barrier: drain publish (vmcnt 0 at s_barrier), fire flag, poll
      __syncthreads();   // S3
      if (tid == 0)
        __hip_atomic_store(&flags[wg * FPAD], t + 2, __ATOMIC_RELAXED, __HIP_MEMORY_SCOPE_AGENT);
      if (tid < 32) {
        while (true) {
          int f = __hip_atomic_load(&flags[tid * FPAD], __ATOMIC_RELAXED, __HIP_MEMORY_SCOPE_AGENT);
          if (__all(f >= t + 2)) break;
        }
      }
      __syncthreads();   // S4: release
    }
  }

  // cT from local c state (same thread mapping as gates -> no sync needed)
  #pragma unroll
  for (int u = 0; u < 2; u++) {
    int idx = tid + u * THR;
    if (idx < 512) {
      int b = idx & 31, c = idx >> 5;
      out[(size_t)cB * cT * cH + (size_t)cB * cH + (size_t)b * cH + ci0 + c] = c_lds[c * 32 + b];
    }
  }
}

extern "C" void kernel_launch(void* const* d_in, const int* in_sizes, int n_in,
                              void* d_out, int out_size, void* d_ws, size_t ws_size,
                              hipStream_t stream) {
  const float* x       = (const float*)d_in[0];
  const int* lengths   = (const int*)d_in[1];
  const float* Wi      = (const float*)d_in[2];
  const float* bi      = (const float*)d_in[3];
  const float* Ws      = (const float*)d_in[4];
  const float* bs      = (const float*)d_in[5];
  float* out = (float*)d_out;

  char* ws = (char*)d_ws;
  int* flags = (int*)ws;                                    // 32 * 64B padded flags
  unsigned short* hbuf = (unsigned short*)(ws + 4096);      // 2*32*512*2 = 64KB
  unsigned short* pi   = (unsigned short*)(ws + (1 << 20)); // [512][3072][32] bf16

  hipMemsetAsync(flags, 0, NWG * FPAD * sizeof(int), stream);
  dim3 grid1(cKI / 128, (cB * cT) / 128);
  gemm_pi<<<grid1, 256, 0, stream>>>(x, Wi, bi, pi);
  lstm_rec<<<NWG, THR, 0, stream>>>(pi, Ws, bs, lengths, hbuf, flags, out);
}